// Round 2
// baseline (2261.731 us; speedup 1.0000x reference)
//
#include <hip/hip_runtime.h>
#include <math.h>

#define WD 128

// ---- ordered-uint encoding for f32 atomic max ----
__device__ __forceinline__ unsigned ord_encode(float f) {
    unsigned u = __float_as_uint(f);
    return (u & 0x80000000u) ? ~u : (u | 0x80000000u);
}
__device__ __forceinline__ float ord_decode(unsigned e) {
    unsigned u = (e & 0x80000000u) ? (e & 0x7fffffffu) : ~e;
    return __uint_as_float(u);
}
#define ORD_NEG_INF 0x007FFFFFu  // ord_encode(-inf)

// y[i][j] = sum_k x[i][k] * We[k*WD + j], k < 128 (first 128 rows of W_edge)
__global__ __launch_bounds__(256) void gemm_y(const float* __restrict__ x,
                                              const float* __restrict__ We,
                                              float* __restrict__ y, int n) {
    __shared__ float xs[8][WD];
    int j = threadIdx.x & 127;
    int half = threadIdx.x >> 7;  // 0..1
    int row0 = blockIdx.x * 8;
    for (int t = threadIdx.x; t < 8 * WD; t += 256) {
        int r = t >> 7, c = t & 127;
        int gr = row0 + r;
        xs[r][c] = (gr < n) ? x[(size_t)gr * WD + c] : 0.f;
    }
    __syncthreads();
    float acc[4] = {0.f, 0.f, 0.f, 0.f};
    #pragma unroll 8
    for (int k = 0; k < WD; ++k) {
        float w = We[k * WD + j];
        acc[0] = fmaf(xs[half + 0][k], w, acc[0]);
        acc[1] = fmaf(xs[half + 2][k], w, acc[1]);
        acc[2] = fmaf(xs[half + 4][k], w, acc[2]);
        acc[3] = fmaf(xs[half + 6][k], w, acc[3]);
    }
    #pragma unroll
    for (int q = 0; q < 4; ++q) {
        int gr = row0 + half + q * 2;
        if (gr < n) y[(size_t)gr * WD + j] = acc[q];
    }
}

__global__ __launch_bounds__(256) void init_maxes(unsigned* __restrict__ mx, int n) {
    int i = blockIdx.x * 256 + threadIdx.x;
    if (i < n) mx[i] = ORD_NEG_INF;
}

// One lane-group of 32 per UNDIRECTED edge, float4 per lane.
// Computes BOTH directions from one set of gathers (x/y at both endpoints).
// 256 threads = 8 undirected edges per block.
__global__ __launch_bounds__(256) void edge_kernel(const int* __restrict__ ei,
                                                   const float* __restrict__ ef,
                                                   const float4* __restrict__ x4,
                                                   const float4* __restrict__ y4,
                                                   const float* __restrict__ We,
                                                   const float* __restrict__ be,
                                                   unsigned* __restrict__ mx,
                                                   int E) {
    int eg = threadIdx.x >> 5;              // edge within block 0..7
    int lane = threadIdx.x & 31;            // 0..31, handles features 4*lane..4*lane+3
    int e = blockIdx.x * 8 + eg;            // undirected edge id
    if (e >= E) return;

    int a = ei[e];          // endpoint A (src of fwd dir)
    int b = ei[E + e];      // endpoint B (dst of fwd dir)
    float ef0 = ef[(size_t)e * 2 + 0];
    float ef1 = ef[(size_t)e * 2 + 1];

    const float4* We128 = (const float4*)(We + 128 * WD);
    const float4* We129 = (const float4*)(We + 129 * WD);
    const float4* be4   = (const float4*)be;

    float4 xa = x4[(size_t)a * 32 + lane];
    float4 xb = x4[(size_t)b * 32 + lane];
    float4 ya = y4[(size_t)a * 32 + lane];
    float4 yb = y4[(size_t)b * 32 + lane];
    float4 w0 = We128[lane];
    float4 w1 = We129[lane];
    float4 bb = be4[lane];

    // edge-feature term c (shared by both directions)
    float c0 = fmaf(ef0, w0.x, fmaf(ef1, w1.x, bb.x));
    float c1 = fmaf(ef0, w0.y, fmaf(ef1, w1.y, bb.y));
    float c2 = fmaf(ef0, w0.z, fmaf(ef1, w1.z, bb.z));
    float c3 = fmaf(ef0, w0.w, fmaf(ef1, w1.w, bb.w));

    float dx0 = xb.x - xa.x, dx1 = xb.y - xa.y, dx2 = xb.z - xa.z, dx3 = xb.w - xa.w;
    float dy0 = yb.x - ya.x, dy1 = yb.y - ya.y, dy2 = yb.z - ya.z, dy3 = yb.w - ya.w;

    // forward direction: src=a, dst=b  -> e_val = (x_b - x_a) + relu((y_b - y_a) + c)
    unsigned* rowB = mx + (size_t)b * WD + lane * 4;
    atomicMax(rowB + 0, ord_encode(dx0 + fmaxf(dy0 + c0, 0.f)));
    atomicMax(rowB + 1, ord_encode(dx1 + fmaxf(dy1 + c1, 0.f)));
    atomicMax(rowB + 2, ord_encode(dx2 + fmaxf(dy2 + c2, 0.f)));
    atomicMax(rowB + 3, ord_encode(dx3 + fmaxf(dy3 + c3, 0.f)));

    // backward direction: src=b, dst=a -> e_val = (x_a - x_b) + relu((y_a - y_b) + c)
    unsigned* rowA = mx + (size_t)a * WD + lane * 4;
    atomicMax(rowA + 0, ord_encode(-dx0 + fmaxf(-dy0 + c0, 0.f)));
    atomicMax(rowA + 1, ord_encode(-dx1 + fmaxf(-dy1 + c1, 0.f)));
    atomicMax(rowA + 2, ord_encode(-dx2 + fmaxf(-dy2 + c2, 0.f)));
    atomicMax(rowA + 3, ord_encode(-dx3 + fmaxf(-dy3 + c3, 0.f)));
}

__global__ __launch_bounds__(256) void decode_maxes(unsigned* __restrict__ buf, int n) {
    int i = blockIdx.x * 256 + threadIdx.x;
    if (i < n) {
        float f = ord_decode(buf[i]);
        if (!isfinite(f)) f = 0.f;
        ((float*)buf)[i] = f;
    }
}

// out[i][j] = x[i][j] + relu( sum_k x[i][k]*Wm[k][j] + sum_k mx[i][k]*Wm[128+k][j] + b[j] )
__global__ __launch_bounds__(256) void gemm_out(const float* __restrict__ x,
                                                const float* __restrict__ mx,
                                                const float* __restrict__ Wm,
                                                const float* __restrict__ b,
                                                float* __restrict__ out, int n) {
    __shared__ float xs[8][2 * WD];
    int j = threadIdx.x & 127;
    int half = threadIdx.x >> 7;  // 0..1
    int row0 = blockIdx.x * 8;
    for (int t = threadIdx.x; t < 8 * 2 * WD; t += 256) {
        int r = t >> 8, c = t & 255;
        int gr = row0 + r;
        float v = 0.f;
        if (gr < n) v = (c < WD) ? x[(size_t)gr * WD + c] : mx[(size_t)gr * WD + (c - WD)];
        xs[r][c] = v;
    }
    __syncthreads();
    float acc[4] = {0.f, 0.f, 0.f, 0.f};
    #pragma unroll 8
    for (int k = 0; k < 2 * WD; ++k) {
        float w = Wm[k * WD + j];
        acc[0] = fmaf(xs[half + 0][k], w, acc[0]);
        acc[1] = fmaf(xs[half + 2][k], w, acc[1]);
        acc[2] = fmaf(xs[half + 4][k], w, acc[2]);
        acc[3] = fmaf(xs[half + 6][k], w, acc[3]);
    }
    float bj = b[j];
    #pragma unroll
    for (int q = 0; q < 4; ++q) {
        int gr = row0 + half + q * 2;
        if (gr < n) {
            float xv = x[(size_t)gr * WD + j];
            out[(size_t)gr * WD + j] = xv + fmaxf(acc[q] + bj, 0.f);
        }
    }
}

extern "C" void kernel_launch(void* const* d_in, const int* in_sizes, int n_in,
                              void* d_out, int out_size, void* d_ws, size_t ws_size,
                              hipStream_t stream) {
    const float* x_p = (const float*)d_in[0];
    const int*   ei  = (const int*)d_in[1];
    const float* ef  = (const float*)d_in[2];
    const float* We  = (const float*)d_in[3];
    const float* be  = (const float*)d_in[4];
    const float* Wm  = (const float*)d_in[5];
    const float* bm  = (const float*)d_in[6];

    int n = in_sizes[0] / WD;        // 50000
    int E = in_sizes[1] / 2;         // 800000

    float*    y  = (float*)d_ws;
    unsigned* mx = (unsigned*)((char*)d_ws + (size_t)n * WD * sizeof(float));

    int nw = n * WD;

    gemm_y<<<(n + 7) / 8, 256, 0, stream>>>(x_p, We, y, n);
    init_maxes<<<(nw + 255) / 256, 256, 0, stream>>>(mx, nw);
    // 8 undirected edges per 256-thread block
    edge_kernel<<<(E + 7) / 8, 256, 0, stream>>>(ei, ef, (const float4*)x_p,
                                                 (const float4*)y, We, be, mx, E);
    decode_maxes<<<(nw + 255) / 256, 256, 0, stream>>>(mx, nw);
    gemm_out<<<(n + 7) / 8, 256, 0, stream>>>(x_p, (const float*)mx, Wm, bm,
                                              (float*)d_out, n);
}

// Round 3
// 537.113 us; speedup vs baseline: 4.2109x; 4.2109x over previous
//
#include <hip/hip_runtime.h>
#include <math.h>

#define WD 128

// ============ GEMM: y = x @ We[:128,:]  ============
__global__ __launch_bounds__(256) void gemm_y(const float* __restrict__ x,
                                              const float* __restrict__ We,
                                              float* __restrict__ y, int n) {
    __shared__ float xs[8][WD];
    int j = threadIdx.x & 127;
    int half = threadIdx.x >> 7;
    int row0 = blockIdx.x * 8;
    for (int t = threadIdx.x; t < 8 * WD; t += 256) {
        int r = t >> 7, c = t & 127;
        int gr = row0 + r;
        xs[r][c] = (gr < n) ? x[(size_t)gr * WD + c] : 0.f;
    }
    __syncthreads();
    float acc[4] = {0.f, 0.f, 0.f, 0.f};
    #pragma unroll 8
    for (int k = 0; k < WD; ++k) {
        float w = We[k * WD + j];
        acc[0] = fmaf(xs[half + 0][k], w, acc[0]);
        acc[1] = fmaf(xs[half + 2][k], w, acc[1]);
        acc[2] = fmaf(xs[half + 4][k], w, acc[2]);
        acc[3] = fmaf(xs[half + 6][k], w, acc[3]);
    }
    #pragma unroll
    for (int q = 0; q < 4; ++q) {
        int gr = row0 + half + q * 2;
        if (gr < n) y[(size_t)gr * WD + j] = acc[q];
    }
}

// ============ CSR build ============
__global__ __launch_bounds__(256) void k_zero(int* __restrict__ cnt, int n) {
    int i = blockIdx.x * 256 + threadIdx.x;
    if (i < n) cnt[i] = 0;
}

__global__ __launch_bounds__(256) void k_count(const int* __restrict__ ei,
                                               int* __restrict__ cnt, int E) {
    int e = blockIdx.x * 256 + threadIdx.x;
    if (e >= E) return;
    atomicAdd(&cnt[ei[e]], 1);
    atomicAdd(&cnt[ei[E + e]], 1);
}

// chunk sums: 256 elements per block
__global__ __launch_bounds__(256) void k_chunksum(const int* __restrict__ cnt,
                                                  int* __restrict__ partials, int n) {
    __shared__ int ls[256];
    int t = threadIdx.x;
    int i = blockIdx.x * 256 + t;
    ls[t] = (i < n) ? cnt[i] : 0;
    __syncthreads();
    for (int s = 128; s > 0; s >>= 1) {
        if (t < s) ls[t] += ls[t + s];
        __syncthreads();
    }
    if (t == 0) partials[blockIdx.x] = ls[0];
}

// single-block exclusive scan of partials (nchunks <= 256)
__global__ __launch_bounds__(256) void k_scanpartials(int* __restrict__ partials,
                                                      int nchunks) {
    __shared__ int ls[256];
    int t = threadIdx.x;
    int v = (t < nchunks) ? partials[t] : 0;
    ls[t] = v;
    __syncthreads();
    for (int s = 1; s < 256; s <<= 1) {
        int tmp = (t >= s) ? ls[t - s] : 0;
        __syncthreads();
        ls[t] += tmp;
        __syncthreads();
    }
    if (t < nchunks) partials[t] = ls[t] - v;  // exclusive
}

// per-chunk exclusive scan + base; writes offsets and cursors
__global__ __launch_bounds__(256) void k_chunkscan(const int* __restrict__ cnt,
                                                   const int* __restrict__ partials,
                                                   int* __restrict__ offsets,
                                                   int* __restrict__ cursors, int n) {
    __shared__ int ls[256];
    int t = threadIdx.x;
    int i = blockIdx.x * 256 + t;
    int v = (i < n) ? cnt[i] : 0;
    ls[t] = v;
    __syncthreads();
    for (int s = 1; s < 256; s <<= 1) {
        int tmp = (t >= s) ? ls[t - s] : 0;
        __syncthreads();
        ls[t] += tmp;
        __syncthreads();
    }
    int off = partials[blockIdx.x] + ls[t] - v;  // exclusive within chunk + base
    if (i < n) {
        offsets[i] = off;
        cursors[i] = off;
        if (i == n - 1) offsets[n] = off + v;
    }
}

// scatter: adj lists grouped by dst; store neighbor id + edge feats
__global__ __launch_bounds__(256) void k_scatter(const int* __restrict__ ei,
                                                 const float* __restrict__ ef,
                                                 int* __restrict__ cursors,
                                                 int* __restrict__ nbr,
                                                 float2* __restrict__ efv, int E) {
    int e = blockIdx.x * 256 + threadIdx.x;
    if (e >= E) return;
    int a = ei[e];
    int b = ei[E + e];
    float2 f = ((const float2*)ef)[e];
    // fwd: src=a dst=b ; bwd: src=b dst=a
    int p1 = atomicAdd(&cursors[b], 1);
    nbr[p1] = a;
    efv[p1] = f;
    int p2 = atomicAdd(&cursors[a], 1);
    nbr[p2] = b;
    efv[p2] = f;
}

// ============ node-parallel segment max (no atomics) ============
// one 128-thread block per node; maxes staged into d_out
__global__ __launch_bounds__(128) void k_nodemax(const int* __restrict__ offsets,
                                                 const int* __restrict__ nbr,
                                                 const float2* __restrict__ efv,
                                                 const float* __restrict__ x,
                                                 const float* __restrict__ y,
                                                 const float* __restrict__ We,
                                                 const float* __restrict__ be,
                                                 float* __restrict__ mxstage, int n) {
    __shared__ int sh_nbr[128];
    __shared__ float2 sh_ef[128];
    int d = blockIdx.x;
    int j = threadIdx.x;
    int beg = offsets[d], end = offsets[d + 1];
    float xd = x[(size_t)d * WD + j];
    float yd = y[(size_t)d * WD + j];
    float w0 = We[128 * WD + j];
    float w1 = We[129 * WD + j];
    float bj = be[j];
    float m = -INFINITY;
    for (int base = beg; base < end; base += 128) {
        int cnt = min(end - base, 128);
        if (j < cnt) {
            sh_nbr[j] = nbr[base + j];
            sh_ef[j] = efv[base + j];
        }
        __syncthreads();
        int i = 0;
        for (; i + 2 <= cnt; i += 2) {
            int s0 = sh_nbr[i], s1 = sh_nbr[i + 1];
            float2 f0 = sh_ef[i], f1 = sh_ef[i + 1];
            float xs0 = x[(size_t)s0 * WD + j];
            float ys0 = y[(size_t)s0 * WD + j];
            float xs1 = x[(size_t)s1 * WD + j];
            float ys1 = y[(size_t)s1 * WD + j];
            float c0 = fmaf(f0.x, w0, fmaf(f0.y, w1, bj));
            float c1 = fmaf(f1.x, w0, fmaf(f1.y, w1, bj));
            m = fmaxf(m, (xd - xs0) + fmaxf((yd - ys0) + c0, 0.f));
            m = fmaxf(m, (xd - xs1) + fmaxf((yd - ys1) + c1, 0.f));
        }
        if (i < cnt) {
            int s0 = sh_nbr[i];
            float2 f0 = sh_ef[i];
            float xs0 = x[(size_t)s0 * WD + j];
            float ys0 = y[(size_t)s0 * WD + j];
            float c0 = fmaf(f0.x, w0, fmaf(f0.y, w1, bj));
            m = fmaxf(m, (xd - xs0) + fmaxf((yd - ys0) + c0, 0.f));
        }
        __syncthreads();
    }
    mxstage[(size_t)d * WD + j] = (beg < end) ? m : 0.f;
}

// ============ out = x + relu([x, mx] @ Wm + b); mx staged in d_out ============
__global__ __launch_bounds__(256) void gemm_out(const float* __restrict__ x,
                                                const float* __restrict__ mx,
                                                const float* __restrict__ Wm,
                                                const float* __restrict__ b,
                                                float* __restrict__ out, int n) {
    __shared__ float xs[8][2 * WD];
    int j = threadIdx.x & 127;
    int half = threadIdx.x >> 7;
    int row0 = blockIdx.x * 8;
    for (int t = threadIdx.x; t < 8 * 2 * WD; t += 256) {
        int r = t >> 8, c = t & 255;
        int gr = row0 + r;
        float v = 0.f;
        if (gr < n) v = (c < WD) ? x[(size_t)gr * WD + c] : mx[(size_t)gr * WD + (c - WD)];
        xs[r][c] = v;
    }
    __syncthreads();
    float acc[4] = {0.f, 0.f, 0.f, 0.f};
    #pragma unroll 8
    for (int k = 0; k < 2 * WD; ++k) {
        float w = Wm[k * WD + j];
        acc[0] = fmaf(xs[half + 0][k], w, acc[0]);
        acc[1] = fmaf(xs[half + 2][k], w, acc[1]);
        acc[2] = fmaf(xs[half + 4][k], w, acc[2]);
        acc[3] = fmaf(xs[half + 6][k], w, acc[3]);
    }
    float bj = b[j];
    #pragma unroll
    for (int q = 0; q < 4; ++q) {
        int gr = row0 + half + q * 2;
        if (gr < n) {
            float xv = x[(size_t)gr * WD + j];
            out[(size_t)gr * WD + j] = xv + fmaxf(acc[q] + bj, 0.f);
        }
    }
}

extern "C" void kernel_launch(void* const* d_in, const int* in_sizes, int n_in,
                              void* d_out, int out_size, void* d_ws, size_t ws_size,
                              hipStream_t stream) {
    const float* x_p = (const float*)d_in[0];
    const int*   ei  = (const int*)d_in[1];
    const float* ef  = (const float*)d_in[2];
    const float* We  = (const float*)d_in[3];
    const float* be  = (const float*)d_in[4];
    const float* Wm  = (const float*)d_in[5];
    const float* bm  = (const float*)d_in[6];

    int n = in_sizes[0] / WD;   // 50000
    int E = in_sizes[1] / 2;    // 800000
    int E2 = 2 * E;

    // ---- workspace layout ----
    char* p = (char*)d_ws;
    float* y = (float*)p;                 p += (size_t)n * WD * sizeof(float);   // 25.6 MB
    int* offsets = (int*)p;               p += ((size_t)(n + 1) * 4 + 15) & ~15ull;
    int* cursors = (int*)p;               p += ((size_t)n * 4 + 15) & ~15ull;    // doubles as counts
    int* partials = (int*)p;              p += 1024 * 4;
    int* nbr = (int*)p;                   p += (size_t)E2 * 4;                   // 6.4 MB
    float2* efv = (float2*)p;             p += (size_t)E2 * 8;                   // 12.8 MB

    int nchunks = (n + 255) / 256;  // 196 (must be <= 256)

    gemm_y<<<(n + 7) / 8, 256, 0, stream>>>(x_p, We, y, n);

    k_zero<<<(n + 255) / 256, 256, 0, stream>>>(cursors, n);
    k_count<<<(E + 255) / 256, 256, 0, stream>>>(ei, cursors, E);
    k_chunksum<<<nchunks, 256, 0, stream>>>(cursors, partials, n);
    k_scanpartials<<<1, 256, 0, stream>>>(partials, nchunks);
    k_chunkscan<<<nchunks, 256, 0, stream>>>(cursors, partials, offsets, cursors, n);
    k_scatter<<<(E + 255) / 256, 256, 0, stream>>>(ei, ef, cursors, nbr, efv, E);

    // maxes staged in d_out, then gemm_out reads it into LDS and overwrites
    k_nodemax<<<n, 128, 0, stream>>>(offsets, nbr, efv, x_p, y, We, be,
                                     (float*)d_out, n);
    gemm_out<<<(n + 7) / 8, 256, 0, stream>>>(x_p, (const float*)d_out, Wm, bm,
                                              (float*)d_out, n);
}

// Round 4
// 446.292 us; speedup vs baseline: 5.0678x; 1.2035x over previous
//
#include <hip/hip_runtime.h>
#include <math.h>

#define WD 128

// ---- bf16 round-to-nearest-even, low 16 bits ----
__device__ __forceinline__ unsigned bf16_rne(float f) {
    unsigned u = __float_as_uint(f);
    return (u + 0x7FFFu + ((u >> 16) & 1u)) >> 16;
}
__device__ __forceinline__ float bf16_lo(unsigned p) {  // low bf16 -> f32
    return __uint_as_float(p << 16);
}
__device__ __forceinline__ float bf16_hi(unsigned p) {  // high bf16 -> f32
    return __uint_as_float(p & 0xFFFF0000u);
}

// ============ GEMM: y = x @ We[:128,:]; writes packed {bf16(x), bf16(y)} ============
__global__ __launch_bounds__(512) void gemm_y_pack(const float* __restrict__ x,
                                                   const float* __restrict__ We,
                                                   unsigned* __restrict__ xy, int n) {
    __shared__ float xs[16][WD];
    int j = threadIdx.x & 127;
    int q4 = threadIdx.x >> 7;  // 0..3
    int row0 = blockIdx.x * 16;
    for (int t = threadIdx.x; t < 16 * WD; t += 512) {
        int r = t >> 7, c = t & 127;
        int gr = row0 + r;
        xs[r][c] = (gr < n) ? x[(size_t)gr * WD + c] : 0.f;
    }
    __syncthreads();
    float acc[4] = {0.f, 0.f, 0.f, 0.f};
    #pragma unroll 8
    for (int k = 0; k < WD; ++k) {
        float w = We[k * WD + j];
        acc[0] = fmaf(xs[q4 + 0][k], w, acc[0]);
        acc[1] = fmaf(xs[q4 + 4][k], w, acc[1]);
        acc[2] = fmaf(xs[q4 + 8][k], w, acc[2]);
        acc[3] = fmaf(xs[q4 + 12][k], w, acc[3]);
    }
    #pragma unroll
    for (int q = 0; q < 4; ++q) {
        int r = q4 + q * 4;
        int gr = row0 + r;
        if (gr < n) {
            unsigned p = bf16_rne(xs[r][j]) | (bf16_rne(acc[q]) << 16);
            xy[(size_t)gr * WD + j] = p;
        }
    }
}

// ============ CSR build ============
__global__ __launch_bounds__(256) void k_zero(int* __restrict__ cnt, int n) {
    int i = blockIdx.x * 256 + threadIdx.x;
    if (i < n) cnt[i] = 0;
}

__global__ __launch_bounds__(256) void k_count(const int* __restrict__ ei,
                                               int* __restrict__ cnt, int E) {
    int e = blockIdx.x * 256 + threadIdx.x;
    if (e >= E) return;
    atomicAdd(&cnt[ei[e]], 1);
    atomicAdd(&cnt[ei[E + e]], 1);
}

__global__ __launch_bounds__(256) void k_chunksum(const int* __restrict__ cnt,
                                                  int* __restrict__ partials, int n) {
    __shared__ int ls[256];
    int t = threadIdx.x;
    int i = blockIdx.x * 256 + t;
    ls[t] = (i < n) ? cnt[i] : 0;
    __syncthreads();
    for (int s = 128; s > 0; s >>= 1) {
        if (t < s) ls[t] += ls[t + s];
        __syncthreads();
    }
    if (t == 0) partials[blockIdx.x] = ls[0];
}

__global__ __launch_bounds__(256) void k_scanpartials(int* __restrict__ partials,
                                                      int nchunks) {
    __shared__ int ls[256];
    int t = threadIdx.x;
    int v = (t < nchunks) ? partials[t] : 0;
    ls[t] = v;
    __syncthreads();
    for (int s = 1; s < 256; s <<= 1) {
        int tmp = (t >= s) ? ls[t - s] : 0;
        __syncthreads();
        ls[t] += tmp;
        __syncthreads();
    }
    if (t < nchunks) partials[t] = ls[t] - v;  // exclusive
}

__global__ __launch_bounds__(256) void k_chunkscan(const int* __restrict__ cnt,
                                                   const int* __restrict__ partials,
                                                   int* __restrict__ offsets,
                                                   int* __restrict__ cursors, int n) {
    __shared__ int ls[256];
    int t = threadIdx.x;
    int i = blockIdx.x * 256 + t;
    int v = (i < n) ? cnt[i] : 0;
    ls[t] = v;
    __syncthreads();
    for (int s = 1; s < 256; s <<= 1) {
        int tmp = (t >= s) ? ls[t - s] : 0;
        __syncthreads();
        ls[t] += tmp;
        __syncthreads();
    }
    int off = partials[blockIdx.x] + ls[t] - v;
    if (i < n) {
        offsets[i] = off;
        cursors[i] = off;
        if (i == n - 1) offsets[n] = off + v;
    }
}

// scatter: adj entry = {nbr, ef packed as 2xbf16}, single 8-B store per directed edge
__global__ __launch_bounds__(256) void k_scatter(const int* __restrict__ ei,
                                                 const float* __restrict__ ef,
                                                 int* __restrict__ cursors,
                                                 int2* __restrict__ adj, int E) {
    int e = blockIdx.x * 256 + threadIdx.x;
    if (e >= E) return;
    int a = ei[e];
    int b = ei[E + e];
    float2 f = ((const float2*)ef)[e];
    int efp = (int)(bf16_rne(f.x) | (bf16_rne(f.y) << 16));
    int p1 = atomicAdd(&cursors[b], 1);
    int2 v1; v1.x = a; v1.y = efp;
    adj[p1] = v1;
    int p2 = atomicAdd(&cursors[a], 1);
    int2 v2; v2.x = b; v2.y = efp;
    adj[p2] = v2;
}

// ============ node-parallel segment max (no atomics), packed bf16 gathers ============
__global__ __launch_bounds__(128) void k_nodemax(const int* __restrict__ offsets,
                                                 const int2* __restrict__ adj,
                                                 const unsigned* __restrict__ xy,
                                                 const float* __restrict__ We,
                                                 const float* __restrict__ be,
                                                 float* __restrict__ mxstage, int n) {
    __shared__ int2 sh[128];
    int d = blockIdx.x;
    int j = threadIdx.x;
    int beg = offsets[d], end = offsets[d + 1];
    unsigned pd = xy[(size_t)d * WD + j];
    float xd = bf16_lo(pd), yd = bf16_hi(pd);
    float w0 = We[128 * WD + j];
    float w1 = We[129 * WD + j];
    float bj = be[j];
    float m = -INFINITY;
    for (int base = beg; base < end; base += 128) {
        int cnt = min(end - base, 128);
        if (j < cnt) sh[j] = adj[base + j];
        __syncthreads();
        int i = 0;
        for (; i + 2 <= cnt; i += 2) {
            int2 v0 = sh[i], v1 = sh[i + 1];
            unsigned p0 = xy[(size_t)v0.x * WD + j];
            unsigned p1 = xy[(size_t)v1.x * WD + j];
            unsigned e0 = (unsigned)v0.y, e1 = (unsigned)v1.y;
            float c0 = fmaf(bf16_lo(e0), w0, fmaf(bf16_hi(e0), w1, bj));
            float c1 = fmaf(bf16_lo(e1), w0, fmaf(bf16_hi(e1), w1, bj));
            m = fmaxf(m, (xd - bf16_lo(p0)) + fmaxf((yd - bf16_hi(p0)) + c0, 0.f));
            m = fmaxf(m, (xd - bf16_lo(p1)) + fmaxf((yd - bf16_hi(p1)) + c1, 0.f));
        }
        if (i < cnt) {
            int2 v0 = sh[i];
            unsigned p0 = xy[(size_t)v0.x * WD + j];
            unsigned e0 = (unsigned)v0.y;
            float c0 = fmaf(bf16_lo(e0), w0, fmaf(bf16_hi(e0), w1, bj));
            m = fmaxf(m, (xd - bf16_lo(p0)) + fmaxf((yd - bf16_hi(p0)) + c0, 0.f));
        }
        __syncthreads();
    }
    mxstage[(size_t)d * WD + j] = (beg < end) ? m : 0.f;
}

// ============ out = x + relu([x, mx] @ Wm + b); mx staged in d_out ============
__global__ __launch_bounds__(512) void gemm_out(const float* __restrict__ x,
                                                const float* __restrict__ mx,
                                                const float* __restrict__ Wm,
                                                const float* __restrict__ b,
                                                float* __restrict__ out, int n) {
    __shared__ float xs[16][2 * WD];
    int j = threadIdx.x & 127;
    int q4 = threadIdx.x >> 7;  // 0..3
    int row0 = blockIdx.x * 16;
    for (int t = threadIdx.x; t < 16 * 2 * WD; t += 512) {
        int r = t >> 8, c = t & 255;
        int gr = row0 + r;
        float v = 0.f;
        if (gr < n) v = (c < WD) ? x[(size_t)gr * WD + c] : mx[(size_t)gr * WD + (c - WD)];
        xs[r][c] = v;
    }
    __syncthreads();
    float acc[4] = {0.f, 0.f, 0.f, 0.f};
    #pragma unroll 8
    for (int k = 0; k < 2 * WD; ++k) {
        float w = Wm[k * WD + j];
        acc[0] = fmaf(xs[q4 + 0][k], w, acc[0]);
        acc[1] = fmaf(xs[q4 + 4][k], w, acc[1]);
        acc[2] = fmaf(xs[q4 + 8][k], w, acc[2]);
        acc[3] = fmaf(xs[q4 + 12][k], w, acc[3]);
    }
    float bj = b[j];
    #pragma unroll
    for (int q = 0; q < 4; ++q) {
        int gr = row0 + q4 + q * 4;
        if (gr < n) {
            float xv = x[(size_t)gr * WD + j];
            out[(size_t)gr * WD + j] = xv + fmaxf(acc[q] + bj, 0.f);
        }
    }
}

extern "C" void kernel_launch(void* const* d_in, const int* in_sizes, int n_in,
                              void* d_out, int out_size, void* d_ws, size_t ws_size,
                              hipStream_t stream) {
    const float* x_p = (const float*)d_in[0];
    const int*   ei  = (const int*)d_in[1];
    const float* ef  = (const float*)d_in[2];
    const float* We  = (const float*)d_in[3];
    const float* be  = (const float*)d_in[4];
    const float* Wm  = (const float*)d_in[5];
    const float* bm  = (const float*)d_in[6];

    int n = in_sizes[0] / WD;   // 50000
    int E = in_sizes[1] / 2;    // 800000
    int E2 = 2 * E;

    // ---- workspace layout ----
    char* p = (char*)d_ws;
    unsigned* xy = (unsigned*)p;          p += (size_t)n * WD * sizeof(unsigned);  // 25.6 MB
    int* offsets = (int*)p;               p += ((size_t)(n + 1) * 4 + 15) & ~15ull;
    int* cursors = (int*)p;               p += ((size_t)n * 4 + 15) & ~15ull;
    int* partials = (int*)p;              p += 1024 * 4;
    int2* adj = (int2*)p;                 p += (size_t)E2 * 8;                     // 12.8 MB

    int nchunks = (n + 255) / 256;  // 196 (<= 256)

    gemm_y_pack<<<(n + 15) / 16, 512, 0, stream>>>(x_p, We, xy, n);

    k_zero<<<(n + 255) / 256, 256, 0, stream>>>(cursors, n);
    k_count<<<(E + 255) / 256, 256, 0, stream>>>(ei, cursors, E);
    k_chunksum<<<nchunks, 256, 0, stream>>>(cursors, partials, n);
    k_scanpartials<<<1, 256, 0, stream>>>(partials, nchunks);
    k_chunkscan<<<nchunks, 256, 0, stream>>>(cursors, partials, offsets, cursors, n);
    k_scatter<<<(E + 255) / 256, 256, 0, stream>>>(ei, ef, cursors, adj, E);

    k_nodemax<<<n, 128, 0, stream>>>(offsets, adj, xy, We, be, (float*)d_out, n);
    gemm_out<<<(n + 15) / 16, 512, 0, stream>>>(x_p, (const float*)d_out, Wm, bm,
                                                (float*)d_out, n);
}

// Round 5
// 432.645 us; speedup vs baseline: 5.2277x; 1.0315x over previous
//
#include <hip/hip_runtime.h>
#include <math.h>

#define WD 128

// ---- bf16 round-to-nearest-even, low 16 bits ----
__device__ __forceinline__ unsigned bf16_rne(float f) {
    unsigned u = __float_as_uint(f);
    return (u + 0x7FFFu + ((u >> 16) & 1u)) >> 16;
}
__device__ __forceinline__ float bf16_lo(unsigned p) {  // low bf16 -> f32
    return __uint_as_float(p << 16);
}
__device__ __forceinline__ float bf16_hi(unsigned p) {  // high bf16 -> f32
    return __uint_as_float(p & 0xFFFF0000u);
}

// ============ GEMM: y = x @ We[:128,:]; writes packed {bf16(x), bf16(y)} ============
__global__ __launch_bounds__(512) void gemm_y_pack(const float* __restrict__ x,
                                                   const float* __restrict__ We,
                                                   unsigned* __restrict__ xy, int n) {
    __shared__ float xs[16][WD];
    int j = threadIdx.x & 127;
    int q4 = threadIdx.x >> 7;  // 0..3
    int row0 = blockIdx.x * 16;
    for (int t = threadIdx.x; t < 16 * WD; t += 512) {
        int r = t >> 7, c = t & 127;
        int gr = row0 + r;
        xs[r][c] = (gr < n) ? x[(size_t)gr * WD + c] : 0.f;
    }
    __syncthreads();
    float acc[4] = {0.f, 0.f, 0.f, 0.f};
    #pragma unroll 8
    for (int k = 0; k < WD; ++k) {
        float w = We[k * WD + j];
        acc[0] = fmaf(xs[q4 + 0][k], w, acc[0]);
        acc[1] = fmaf(xs[q4 + 4][k], w, acc[1]);
        acc[2] = fmaf(xs[q4 + 8][k], w, acc[2]);
        acc[3] = fmaf(xs[q4 + 12][k], w, acc[3]);
    }
    #pragma unroll
    for (int q = 0; q < 4; ++q) {
        int r = q4 + q * 4;
        int gr = row0 + r;
        if (gr < n) {
            unsigned p = bf16_rne(xs[r][j]) | (bf16_rne(acc[q]) << 16);
            xy[(size_t)gr * WD + j] = p;
        }
    }
}

// ============ CSR build ============
// 4 edges per thread, vector loads, independent atomics
__global__ __launch_bounds__(256) void k_count(const int* __restrict__ ei,
                                               int* __restrict__ cnt, int E) {
    int base = (blockIdx.x * 256 + threadIdx.x) * 4;
    if (base + 4 <= E) {
        int4 a = *(const int4*)(ei + base);
        int4 b = *(const int4*)(ei + E + base);
        atomicAdd(&cnt[a.x], 1); atomicAdd(&cnt[b.x], 1);
        atomicAdd(&cnt[a.y], 1); atomicAdd(&cnt[b.y], 1);
        atomicAdd(&cnt[a.z], 1); atomicAdd(&cnt[b.z], 1);
        atomicAdd(&cnt[a.w], 1); atomicAdd(&cnt[b.w], 1);
    } else {
        for (int e = base; e < E; ++e) {
            atomicAdd(&cnt[ei[e]], 1);
            atomicAdd(&cnt[ei[E + e]], 1);
        }
    }
}

__global__ __launch_bounds__(256) void k_chunksum(const int* __restrict__ cnt,
                                                  int* __restrict__ partials, int n) {
    __shared__ int ls[256];
    int t = threadIdx.x;
    int i = blockIdx.x * 256 + t;
    ls[t] = (i < n) ? cnt[i] : 0;
    __syncthreads();
    for (int s = 128; s > 0; s >>= 1) {
        if (t < s) ls[t] += ls[t + s];
        __syncthreads();
    }
    if (t == 0) partials[blockIdx.x] = ls[0];
}

__global__ __launch_bounds__(256) void k_scanpartials(int* __restrict__ partials,
                                                      int nchunks) {
    __shared__ int ls[256];
    int t = threadIdx.x;
    int v = (t < nchunks) ? partials[t] : 0;
    ls[t] = v;
    __syncthreads();
    for (int s = 1; s < 256; s <<= 1) {
        int tmp = (t >= s) ? ls[t - s] : 0;
        __syncthreads();
        ls[t] += tmp;
        __syncthreads();
    }
    if (t < nchunks) partials[t] = ls[t] - v;  // exclusive
}

__global__ __launch_bounds__(256) void k_chunkscan(const int* __restrict__ cnt,
                                                   const int* __restrict__ partials,
                                                   int* __restrict__ offsets,
                                                   int* __restrict__ cursors, int n) {
    __shared__ int ls[256];
    int t = threadIdx.x;
    int i = blockIdx.x * 256 + t;
    int v = (i < n) ? cnt[i] : 0;
    ls[t] = v;
    __syncthreads();
    for (int s = 1; s < 256; s <<= 1) {
        int tmp = (t >= s) ? ls[t - s] : 0;
        __syncthreads();
        ls[t] += tmp;
        __syncthreads();
    }
    int off = partials[blockIdx.x] + ls[t] - v;
    if (i < n) {
        offsets[i] = off;
        cursors[i] = off;
        if (i == n - 1) offsets[n] = off + v;
    }
}

// scatter: 4 edges/thread; 8 independent atomics then 8 independent stores
__global__ __launch_bounds__(256) void k_scatter(const int* __restrict__ ei,
                                                 const float* __restrict__ ef,
                                                 int* __restrict__ cursors,
                                                 int2* __restrict__ adj, int E) {
    int base = (blockIdx.x * 256 + threadIdx.x) * 4;
    if (base + 4 <= E) {
        int4 a = *(const int4*)(ei + base);
        int4 b = *(const int4*)(ei + E + base);
        float4 f01 = *(const float4*)(ef + 2 * base);
        float4 f23 = *(const float4*)(ef + 2 * base + 4);
        int ep0 = (int)(bf16_rne(f01.x) | (bf16_rne(f01.y) << 16));
        int ep1 = (int)(bf16_rne(f01.z) | (bf16_rne(f01.w) << 16));
        int ep2 = (int)(bf16_rne(f23.x) | (bf16_rne(f23.y) << 16));
        int ep3 = (int)(bf16_rne(f23.z) | (bf16_rne(f23.w) << 16));
        int pb0 = atomicAdd(&cursors[b.x], 1);
        int pa0 = atomicAdd(&cursors[a.x], 1);
        int pb1 = atomicAdd(&cursors[b.y], 1);
        int pa1 = atomicAdd(&cursors[a.y], 1);
        int pb2 = atomicAdd(&cursors[b.z], 1);
        int pa2 = atomicAdd(&cursors[a.z], 1);
        int pb3 = atomicAdd(&cursors[b.w], 1);
        int pa3 = atomicAdd(&cursors[a.w], 1);
        int2 v;
        v.x = a.x; v.y = ep0; adj[pb0] = v;
        v.x = b.x;            adj[pa0] = v;
        v.x = a.y; v.y = ep1; adj[pb1] = v;
        v.x = b.y;            adj[pa1] = v;
        v.x = a.z; v.y = ep2; adj[pb2] = v;
        v.x = b.z;            adj[pa2] = v;
        v.x = a.w; v.y = ep3; adj[pb3] = v;
        v.x = b.w;            adj[pa3] = v;
    } else {
        for (int e = base; e < E; ++e) {
            int aa = ei[e];
            int bb = ei[E + e];
            float2 f = ((const float2*)ef)[e];
            int efp = (int)(bf16_rne(f.x) | (bf16_rne(f.y) << 16));
            int p1 = atomicAdd(&cursors[bb], 1);
            int2 v1; v1.x = aa; v1.y = efp;
            adj[p1] = v1;
            int p2 = atomicAdd(&cursors[aa], 1);
            int2 v2; v2.x = bb; v2.y = efp;
            adj[p2] = v2;
        }
    }
}

// ============ node-parallel segment max (no atomics), packed bf16 gathers ============
__global__ __launch_bounds__(128) void k_nodemax(const int* __restrict__ offsets,
                                                 const int2* __restrict__ adj,
                                                 const unsigned* __restrict__ xy,
                                                 const float* __restrict__ We,
                                                 const float* __restrict__ be,
                                                 float* __restrict__ mxstage, int n) {
    __shared__ int2 sh[128];
    int d = blockIdx.x;
    int j = threadIdx.x;
    int beg = offsets[d], end = offsets[d + 1];
    unsigned pd = xy[(size_t)d * WD + j];
    float xd = bf16_lo(pd), yd = bf16_hi(pd);
    float w0 = We[128 * WD + j];
    float w1 = We[129 * WD + j];
    float bj = be[j];
    float m = -INFINITY;
    for (int base = beg; base < end; base += 128) {
        int cnt = min(end - base, 128);
        if (j < cnt) sh[j] = adj[base + j];
        __syncthreads();
        int i = 0;
        for (; i + 4 <= cnt; i += 4) {
            int2 v0 = sh[i], v1 = sh[i + 1], v2 = sh[i + 2], v3 = sh[i + 3];
            unsigned p0 = xy[(size_t)v0.x * WD + j];
            unsigned p1 = xy[(size_t)v1.x * WD + j];
            unsigned p2 = xy[(size_t)v2.x * WD + j];
            unsigned p3 = xy[(size_t)v3.x * WD + j];
            unsigned e0 = (unsigned)v0.y, e1 = (unsigned)v1.y;
            unsigned e2 = (unsigned)v2.y, e3 = (unsigned)v3.y;
            float c0 = fmaf(bf16_lo(e0), w0, fmaf(bf16_hi(e0), w1, bj));
            float c1 = fmaf(bf16_lo(e1), w0, fmaf(bf16_hi(e1), w1, bj));
            float c2 = fmaf(bf16_lo(e2), w0, fmaf(bf16_hi(e2), w1, bj));
            float c3 = fmaf(bf16_lo(e3), w0, fmaf(bf16_hi(e3), w1, bj));
            float t0 = (xd - bf16_lo(p0)) + fmaxf((yd - bf16_hi(p0)) + c0, 0.f);
            float t1 = (xd - bf16_lo(p1)) + fmaxf((yd - bf16_hi(p1)) + c1, 0.f);
            float t2 = (xd - bf16_lo(p2)) + fmaxf((yd - bf16_hi(p2)) + c2, 0.f);
            float t3 = (xd - bf16_lo(p3)) + fmaxf((yd - bf16_hi(p3)) + c3, 0.f);
            m = fmaxf(m, fmaxf(fmaxf(t0, t1), fmaxf(t2, t3)));
        }
        for (; i < cnt; ++i) {
            int2 v0 = sh[i];
            unsigned p0 = xy[(size_t)v0.x * WD + j];
            unsigned e0 = (unsigned)v0.y;
            float c0 = fmaf(bf16_lo(e0), w0, fmaf(bf16_hi(e0), w1, bj));
            m = fmaxf(m, (xd - bf16_lo(p0)) + fmaxf((yd - bf16_hi(p0)) + c0, 0.f));
        }
        __syncthreads();
    }
    mxstage[(size_t)d * WD + j] = (beg < end) ? m : 0.f;
}

// ============ out = x + relu([x, mx] @ Wm + b); mx staged in d_out ============
__global__ __launch_bounds__(512) void gemm_out(const float* __restrict__ x,
                                                const float* __restrict__ mx,
                                                const float* __restrict__ Wm,
                                                const float* __restrict__ b,
                                                float* __restrict__ out, int n) {
    __shared__ float xs[16][2 * WD];
    int j = threadIdx.x & 127;
    int q4 = threadIdx.x >> 7;  // 0..3
    int row0 = blockIdx.x * 16;
    for (int t = threadIdx.x; t < 16 * 2 * WD; t += 512) {
        int r = t >> 8, c = t & 255;
        int gr = row0 + r;
        float v = 0.f;
        if (gr < n) v = (c < WD) ? x[(size_t)gr * WD + c] : mx[(size_t)gr * WD + (c - WD)];
        xs[r][c] = v;
    }
    __syncthreads();
    float acc[4] = {0.f, 0.f, 0.f, 0.f};
    #pragma unroll 8
    for (int k = 0; k < 2 * WD; ++k) {
        float w = Wm[k * WD + j];
        acc[0] = fmaf(xs[q4 + 0][k], w, acc[0]);
        acc[1] = fmaf(xs[q4 + 4][k], w, acc[1]);
        acc[2] = fmaf(xs[q4 + 8][k], w, acc[2]);
        acc[3] = fmaf(xs[q4 + 12][k], w, acc[3]);
    }
    float bj = b[j];
    #pragma unroll
    for (int q = 0; q < 4; ++q) {
        int gr = row0 + q4 + q * 4;
        if (gr < n) {
            float xv = x[(size_t)gr * WD + j];
            out[(size_t)gr * WD + j] = xv + fmaxf(acc[q] + bj, 0.f);
        }
    }
}

extern "C" void kernel_launch(void* const* d_in, const int* in_sizes, int n_in,
                              void* d_out, int out_size, void* d_ws, size_t ws_size,
                              hipStream_t stream) {
    const float* x_p = (const float*)d_in[0];
    const int*   ei  = (const int*)d_in[1];
    const float* ef  = (const float*)d_in[2];
    const float* We  = (const float*)d_in[3];
    const float* be  = (const float*)d_in[4];
    const float* Wm  = (const float*)d_in[5];
    const float* bm  = (const float*)d_in[6];

    int n = in_sizes[0] / WD;   // 50000
    int E = in_sizes[1] / 2;    // 800000
    int E2 = 2 * E;

    // ---- workspace layout ----
    char* p = (char*)d_ws;
    unsigned* xy = (unsigned*)p;          p += (size_t)n * WD * sizeof(unsigned);  // 25.6 MB
    int* offsets = (int*)p;               p += ((size_t)(n + 1) * 4 + 15) & ~15ull;
    int* cursors = (int*)p;               p += ((size_t)n * 4 + 15) & ~15ull;
    int* partials = (int*)p;              p += 1024 * 4;
    int2* adj = (int2*)p;                 p += (size_t)E2 * 8;                     // 12.8 MB

    int nchunks = (n + 255) / 256;  // 196 (<= 256)
    int ethreads4 = (E + 3) / 4;

    gemm_y_pack<<<(n + 15) / 16, 512, 0, stream>>>(x_p, We, xy, n);

    hipMemsetAsync(cursors, 0, (size_t)n * sizeof(int), stream);
    k_count<<<(ethreads4 + 255) / 256, 256, 0, stream>>>(ei, cursors, E);
    k_chunksum<<<nchunks, 256, 0, stream>>>(cursors, partials, n);
    k_scanpartials<<<1, 256, 0, stream>>>(partials, nchunks);
    k_chunkscan<<<nchunks, 256, 0, stream>>>(cursors, partials, offsets, cursors, n);
    k_scatter<<<(ethreads4 + 255) / 256, 256, 0, stream>>>(ei, ef, cursors, adj, E);

    k_nodemax<<<n, 128, 0, stream>>>(offsets, adj, xy, We, be, (float*)d_out, n);
    gemm_out<<<(n + 15) / 16, 512, 0, stream>>>(x_p, (const float*)d_out, Wm, bm,
                                                (float*)d_out, n);
}